// Round 1
// baseline (9386.643 us; speedup 1.0000x reference)
//
#include <hip/hip_runtime.h>

#define B_ 16384
#define S_ 336
#define T_ 48
#define IN_ 5
#define H_ 64

// ws float offsets
#define OFF_WE0 0        // [69][256]   k<5: Wih0 cols, k>=5: Whh0 cols
#define OFF_BE0 17664    // [256]
#define OFF_WE1 17920    // [128][256]  k<64: Wih1, k>=64: Whh1
#define OFF_BE1 50688    // [256]
#define OFF_WD0 50944    // [65][256]   k==0: dec_Wih0, k>=1: dec_Whh0
#define OFF_BD0 67584    // [256]
#define OFF_WD1 67840    // [128][256]
#define OFF_BD1 100608   // [256]
#define OFF_FCW 100864   // [64]
#define OFF_FCB 100928   // [1]
#define WS_TOT  100929

__device__ __forceinline__ float fsig(float x) {
    return __builtin_amdgcn_rcpf(1.0f + __expf(-x));
}
__device__ __forceinline__ float ftanh(float x) {
    // tanh(x) = 1 - 2/(exp(2x)+1); saturates correctly at +-inf
    return 1.0f - 2.0f * __builtin_amdgcn_rcpf(1.0f + __expf(2.0f * x));
}

__global__ void prep_kernel(
    const float* __restrict__ eWih0, const float* __restrict__ eWhh0,
    const float* __restrict__ ebih0, const float* __restrict__ ebhh0,
    const float* __restrict__ eWih1, const float* __restrict__ eWhh1,
    const float* __restrict__ ebih1, const float* __restrict__ ebhh1,
    const float* __restrict__ dWih0, const float* __restrict__ dWhh0,
    const float* __restrict__ dbih0, const float* __restrict__ dbhh0,
    const float* __restrict__ dWih1, const float* __restrict__ dWhh1,
    const float* __restrict__ dbih1, const float* __restrict__ dbhh1,
    const float* __restrict__ fcW,  const float* __restrict__ fcb,
    float* __restrict__ ws)
{
    int idx = blockIdx.x * blockDim.x + threadIdx.x;
    if (idx >= WS_TOT) return;
    float v;
    if (idx < OFF_BE0) {
        int k = idx >> 8, jp = idx & 255;
        int u = jp >> 2, g = jp & 3, j = g * 64 + u;
        v = (k < IN_) ? eWih0[j * IN_ + k] : eWhh0[j * 64 + (k - IN_)];
    } else if (idx < OFF_WE1) {
        int jp = idx - OFF_BE0; int u = jp >> 2, g = jp & 3, j = g * 64 + u;
        v = ebih0[j] + ebhh0[j];
    } else if (idx < OFF_BE1) {
        int r = idx - OFF_WE1; int k = r >> 8, jp = r & 255;
        int u = jp >> 2, g = jp & 3, j = g * 64 + u;
        v = (k < 64) ? eWih1[j * 64 + k] : eWhh1[j * 64 + (k - 64)];
    } else if (idx < OFF_WD0) {
        int jp = idx - OFF_BE1; int u = jp >> 2, g = jp & 3, j = g * 64 + u;
        v = ebih1[j] + ebhh1[j];
    } else if (idx < OFF_BD0) {
        int r = idx - OFF_WD0; int k = r >> 8, jp = r & 255;
        int u = jp >> 2, g = jp & 3, j = g * 64 + u;
        v = (k == 0) ? dWih0[j] : dWhh0[j * 64 + (k - 1)];
    } else if (idx < OFF_WD1) {
        int jp = idx - OFF_BD0; int u = jp >> 2, g = jp & 3, j = g * 64 + u;
        v = dbih0[j] + dbhh0[j];
    } else if (idx < OFF_BD1) {
        int r = idx - OFF_WD1; int k = r >> 8, jp = r & 255;
        int u = jp >> 2, g = jp & 3, j = g * 64 + u;
        v = (k < 64) ? dWih1[j * 64 + k] : dWhh1[j * 64 + (k - 64)];
    } else if (idx < OFF_FCW) {
        int jp = idx - OFF_BD1; int u = jp >> 2, g = jp & 3, j = g * 64 + u;
        v = dbih1[j] + dbhh1[j];
    } else if (idx < OFF_FCB) {
        v = fcW[idx - OFF_FCW];
    } else {
        v = fcb[0];
    }
    ws[idx] = v;
}

// Block: 512 threads = 8 waves. lane = batch row within 64-row group,
// wave w owns hidden units [8w, 8w+8) i.e. gate-row indices j' in [32w, 32w+32)
// (j' = u*4+g packing). Weight reads are wave-uniform -> scalar loads.
// h state in LDS transposed [k][row] (conflict-free), double-buffered.
__global__ __launch_bounds__(512, 2) void lstm_kernel(
    const float* __restrict__ src, const float* __restrict__ ws,
    float* __restrict__ out)
{
    __shared__ float Hs[2][2][64][64]; // [layer][buf][k][row] = 64 KiB

    const int tid  = threadIdx.x;
    const int lane = tid & 63;
    const int wave = __builtin_amdgcn_readfirstlane(tid >> 6);
    const int jb   = wave * 32;   // gate-row base within 256
    const int u0   = wave * 8;    // hidden-unit base
    const int row  = blockIdx.x * 64 + lane;

    // zero h state
    for (int i = tid; i < 2 * 2 * 64 * 64; i += 512) ((float*)Hs)[i] = 0.0f;
    __syncthreads();

    const float* we0 = ws + OFF_WE0 + jb;
    const float* be0 = ws + OFF_BE0 + jb;
    const float* we1 = ws + OFF_WE1 + jb;
    const float* be1 = ws + OFF_BE1 + jb;
    const float* wd0 = ws + OFF_WD0 + jb;
    const float* bd0 = ws + OFF_BD0 + jb;
    const float* wd1 = ws + OFF_WD1 + jb;
    const float* bd1 = ws + OFF_BD1 + jb;
    const float* fcw = ws + OFF_FCW;

    float c0[8], c1[8];
    #pragma unroll
    for (int u = 0; u < 8; ++u) { c0[u] = 0.0f; c1[u] = 0.0f; }

    const float* sp = src + (size_t)row * (S_ * IN_);
    int cur = 0;

    // ---------------- encoder ----------------
    #pragma unroll 1
    for (int t = 0; t < S_; ++t) {
        float x[IN_];
        #pragma unroll
        for (int i = 0; i < IN_; ++i) x[i] = sp[i];
        sp += IN_;

        float acc[32];
        #pragma unroll
        for (int j = 0; j < 32; ++j) acc[j] = be0[j];
        #pragma unroll
        for (int k = 0; k < IN_; ++k) {
            #pragma unroll
            for (int j = 0; j < 32; ++j)
                acc[j] = fmaf(we0[k * 256 + j], x[k], acc[j]);
        }
        #pragma unroll 2
        for (int k = 0; k < 64; ++k) {
            float hk = Hs[0][cur][k][lane];
            #pragma unroll
            for (int j = 0; j < 32; ++j)
                acc[j] = fmaf(we0[(IN_ + k) * 256 + j], hk, acc[j]);
        }
        #pragma unroll
        for (int u = 0; u < 8; ++u) {
            float ig = fsig(acc[4 * u + 0]);
            float fg = fsig(acc[4 * u + 1]);
            float gg = ftanh(acc[4 * u + 2]);
            float og = fsig(acc[4 * u + 3]);
            c0[u] = fmaf(fg, c0[u], ig * gg);
            Hs[0][cur ^ 1][u0 + u][lane] = og * ftanh(c0[u]);
        }
        __syncthreads();

        #pragma unroll
        for (int j = 0; j < 32; ++j) acc[j] = be1[j];
        #pragma unroll 2
        for (int k = 0; k < 64; ++k) {
            float hk = Hs[0][cur ^ 1][k][lane];
            #pragma unroll
            for (int j = 0; j < 32; ++j)
                acc[j] = fmaf(we1[k * 256 + j], hk, acc[j]);
        }
        #pragma unroll 2
        for (int k = 0; k < 64; ++k) {
            float hk = Hs[1][cur][k][lane];
            #pragma unroll
            for (int j = 0; j < 32; ++j)
                acc[j] = fmaf(we1[(64 + k) * 256 + j], hk, acc[j]);
        }
        #pragma unroll
        for (int u = 0; u < 8; ++u) {
            float ig = fsig(acc[4 * u + 0]);
            float fg = fsig(acc[4 * u + 1]);
            float gg = ftanh(acc[4 * u + 2]);
            float og = fsig(acc[4 * u + 3]);
            c1[u] = fmaf(fg, c1[u], ig * gg);
            Hs[1][cur ^ 1][u0 + u][lane] = og * ftanh(c1[u]);
        }
        __syncthreads();
        cur ^= 1;
    }

    // ---------------- decoder ----------------
    float xp = src[(size_t)row * (S_ * IN_) + (S_ - 1) * IN_ + 3];
    const float fcb = ws[OFF_FCB];

    #pragma unroll 1
    for (int t = 0; t < T_; ++t) {
        float acc[32];
        #pragma unroll
        for (int j = 0; j < 32; ++j) acc[j] = fmaf(wd0[j], xp, bd0[j]);
        #pragma unroll 2
        for (int k = 0; k < 64; ++k) {
            float hk = Hs[0][cur][k][lane];
            #pragma unroll
            for (int j = 0; j < 32; ++j)
                acc[j] = fmaf(wd0[(1 + k) * 256 + j], hk, acc[j]);
        }
        #pragma unroll
        for (int u = 0; u < 8; ++u) {
            float ig = fsig(acc[4 * u + 0]);
            float fg = fsig(acc[4 * u + 1]);
            float gg = ftanh(acc[4 * u + 2]);
            float og = fsig(acc[4 * u + 3]);
            c0[u] = fmaf(fg, c0[u], ig * gg);
            Hs[0][cur ^ 1][u0 + u][lane] = og * ftanh(c0[u]);
        }
        __syncthreads();

        #pragma unroll
        for (int j = 0; j < 32; ++j) acc[j] = bd1[j];
        #pragma unroll 2
        for (int k = 0; k < 64; ++k) {
            float hk = Hs[0][cur ^ 1][k][lane];
            #pragma unroll
            for (int j = 0; j < 32; ++j)
                acc[j] = fmaf(wd1[k * 256 + j], hk, acc[j]);
        }
        #pragma unroll 2
        for (int k = 0; k < 64; ++k) {
            float hk = Hs[1][cur][k][lane];
            #pragma unroll
            for (int j = 0; j < 32; ++j)
                acc[j] = fmaf(wd1[(64 + k) * 256 + j], hk, acc[j]);
        }
        #pragma unroll
        for (int u = 0; u < 8; ++u) {
            float ig = fsig(acc[4 * u + 0]);
            float fg = fsig(acc[4 * u + 1]);
            float gg = ftanh(acc[4 * u + 2]);
            float og = fsig(acc[4 * u + 3]);
            c1[u] = fmaf(fg, c1[u], ig * gg);
            Hs[1][cur ^ 1][u0 + u][lane] = og * ftanh(c1[u]);
        }
        __syncthreads();

        // fc head: pred = h1_new . fcW + fcb   (every wave computes it; wave 0 stores)
        float p = fcb;
        #pragma unroll 4
        for (int k = 0; k < 64; ++k)
            p = fmaf(fcw[k], Hs[1][cur ^ 1][k][lane], p);
        if (wave == 0) out[(size_t)row * T_ + t] = p;
        xp = p;
        cur ^= 1;
    }
}

extern "C" void kernel_launch(void* const* d_in, const int* in_sizes, int n_in,
                              void* d_out, int out_size, void* d_ws, size_t ws_size,
                              hipStream_t stream)
{
    const float* src = (const float*)d_in[0];
    float* ws  = (float*)d_ws;
    float* out = (float*)d_out;

    prep_kernel<<<(WS_TOT + 255) / 256, 256, 0, stream>>>(
        (const float*)d_in[1],  (const float*)d_in[2],
        (const float*)d_in[3],  (const float*)d_in[4],
        (const float*)d_in[5],  (const float*)d_in[6],
        (const float*)d_in[7],  (const float*)d_in[8],
        (const float*)d_in[9],  (const float*)d_in[10],
        (const float*)d_in[11], (const float*)d_in[12],
        (const float*)d_in[13], (const float*)d_in[14],
        (const float*)d_in[15], (const float*)d_in[16],
        (const float*)d_in[17], (const float*)d_in[18],
        ws);

    lstm_kernel<<<B_ / 64, 512, 0, stream>>>(src, ws, out);
}

// Round 2
// 8087.016 us; speedup vs baseline: 1.1607x; 1.1607x over previous
//
#include <hip/hip_runtime.h>

typedef float f2 __attribute__((ext_vector_type(2)));

#define B_ 16384
#define S_ 336
#define T_ 48
#define IN_ 5
#define H_ 64

// ws float offsets
#define OFF_WE0 0        // [69][256]   k<5: Wih0 cols, k>=5: Whh0 cols
#define OFF_BE0 17664    // [256]
#define OFF_WE1 17920    // [128][256]  k<64: Wih1, k>=64: Whh1
#define OFF_BE1 50688    // [256]
#define OFF_WD0 50944    // [65][256]   k==0: dec_Wih0, k>=1: dec_Whh0
#define OFF_BD0 67584    // [256]
#define OFF_WD1 67840    // [128][256]
#define OFF_BD1 100608   // [256]
#define OFF_FCW 100864   // [64]
#define OFF_FCB 100928   // [1]
#define WS_TOT  100929

__device__ __forceinline__ float fsig(float x) {
    return __builtin_amdgcn_rcpf(1.0f + __expf(-x));
}
__device__ __forceinline__ float ftanh(float x) {
    return 1.0f - 2.0f * __builtin_amdgcn_rcpf(1.0f + __expf(2.0f * x));
}

__global__ void prep_kernel(
    const float* __restrict__ eWih0, const float* __restrict__ eWhh0,
    const float* __restrict__ ebih0, const float* __restrict__ ebhh0,
    const float* __restrict__ eWih1, const float* __restrict__ eWhh1,
    const float* __restrict__ ebih1, const float* __restrict__ ebhh1,
    const float* __restrict__ dWih0, const float* __restrict__ dWhh0,
    const float* __restrict__ dbih0, const float* __restrict__ dbhh0,
    const float* __restrict__ dWih1, const float* __restrict__ dWhh1,
    const float* __restrict__ dbih1, const float* __restrict__ dbhh1,
    const float* __restrict__ fcW,  const float* __restrict__ fcb,
    float* __restrict__ ws)
{
    int idx = blockIdx.x * blockDim.x + threadIdx.x;
    if (idx >= WS_TOT) return;
    float v;
    if (idx < OFF_BE0) {
        int k = idx >> 8, jp = idx & 255;
        int u = jp >> 2, g = jp & 3, j = g * 64 + u;
        v = (k < IN_) ? eWih0[j * IN_ + k] : eWhh0[j * 64 + (k - IN_)];
    } else if (idx < OFF_WE1) {
        int jp = idx - OFF_BE0; int u = jp >> 2, g = jp & 3, j = g * 64 + u;
        v = ebih0[j] + ebhh0[j];
    } else if (idx < OFF_BE1) {
        int r = idx - OFF_WE1; int k = r >> 8, jp = r & 255;
        int u = jp >> 2, g = jp & 3, j = g * 64 + u;
        v = (k < 64) ? eWih1[j * 64 + k] : eWhh1[j * 64 + (k - 64)];
    } else if (idx < OFF_WD0) {
        int jp = idx - OFF_BE1; int u = jp >> 2, g = jp & 3, j = g * 64 + u;
        v = ebih1[j] + ebhh1[j];
    } else if (idx < OFF_BD0) {
        int r = idx - OFF_WD0; int k = r >> 8, jp = r & 255;
        int u = jp >> 2, g = jp & 3, j = g * 64 + u;
        v = (k == 0) ? dWih0[j] : dWhh0[j * 64 + (k - 1)];
    } else if (idx < OFF_WD1) {
        int jp = idx - OFF_BD0; int u = jp >> 2, g = jp & 3, j = g * 64 + u;
        v = dbih0[j] + dbhh0[j];
    } else if (idx < OFF_BD1) {
        int r = idx - OFF_WD1; int k = r >> 8, jp = r & 255;
        int u = jp >> 2, g = jp & 3, j = g * 64 + u;
        v = (k < 64) ? dWih1[j * 64 + k] : dWhh1[j * 64 + (k - 64)];
    } else if (idx < OFF_FCW) {
        int jp = idx - OFF_BD1; int u = jp >> 2, g = jp & 3, j = g * 64 + u;
        v = dbih1[j] + dbhh1[j];
    } else if (idx < OFF_FCB) {
        v = fcW[idx - OFF_FCW];
    } else {
        v = fcb[0];
    }
    ws[idx] = v;
}

// Block: 1024 threads = 16 waves. lane = batch row within 64-row group.
// Wave w owns packed gate-rows [16w, 16w+16) = hidden units [4w, 4w+4).
// (packed j' = u*4+g.) Weight reads wave-uniform -> s_load (64-bit pairs).
// Inner FMA in float2 -> v_pk_fma_f32. h state in LDS transposed [k][row]
// (conflict-free), double-buffered.
__global__ __launch_bounds__(1024) void lstm_kernel(
    const float* __restrict__ src, const float* __restrict__ ws,
    float* __restrict__ out)
{
    __shared__ float Hs[2][2][64][64]; // [layer][buf][k][row] = 64 KiB

    const int tid  = threadIdx.x;
    const int lane = tid & 63;
    const int wave = __builtin_amdgcn_readfirstlane(tid >> 6);
    const int jb   = wave * 16;   // packed gate-row base within 256
    const int u0   = wave * 4;    // hidden-unit base
    const int row  = blockIdx.x * 64 + lane;

    for (int i = tid; i < 2 * 2 * 64 * 64; i += 1024) ((float*)Hs)[i] = 0.0f;
    __syncthreads();

    const f2* we0 = (const f2*)(ws + OFF_WE0 + jb);   // per-k stride 128 f2
    const f2* be0 = (const f2*)(ws + OFF_BE0 + jb);
    const f2* we1 = (const f2*)(ws + OFF_WE1 + jb);
    const f2* be1 = (const f2*)(ws + OFF_BE1 + jb);
    const f2* wd0 = (const f2*)(ws + OFF_WD0 + jb);
    const f2* bd0 = (const f2*)(ws + OFF_BD0 + jb);
    const f2* wd1 = (const f2*)(ws + OFF_WD1 + jb);
    const f2* bd1 = (const f2*)(ws + OFF_BD1 + jb);
    const float* fcw = ws + OFF_FCW;

    float c0[4], c1[4];
    #pragma unroll
    for (int u = 0; u < 4; ++u) { c0[u] = 0.0f; c1[u] = 0.0f; }

    const float* sp = src + (size_t)row * (S_ * IN_);
    int cur = 0;

    float x[IN_];
    #pragma unroll
    for (int i = 0; i < IN_; ++i) x[i] = sp[i];

    // ---------------- encoder ----------------
    #pragma unroll 1
    for (int t = 0; t < S_; ++t) {
        // prefetch next x under this step's compute
        float xn[IN_];
        if (t + 1 < S_) {
            #pragma unroll
            for (int i = 0; i < IN_; ++i) xn[i] = sp[IN_ + i];
        }
        sp += IN_;

        f2 acc[8];
        #pragma unroll
        for (int j = 0; j < 8; ++j) acc[j] = be0[j];
        #pragma unroll
        for (int k = 0; k < IN_; ++k) {
            f2 xs = x[k];
            #pragma unroll
            for (int j = 0; j < 8; ++j)
                acc[j] = __builtin_elementwise_fma(we0[k * 128 + j], xs, acc[j]);
        }
        #pragma unroll 4
        for (int k = 0; k < 64; ++k) {
            f2 hk = Hs[0][cur][k][lane];
            #pragma unroll
            for (int j = 0; j < 8; ++j)
                acc[j] = __builtin_elementwise_fma(we0[(IN_ + k) * 128 + j], hk, acc[j]);
        }
        #pragma unroll
        for (int u = 0; u < 4; ++u) {
            float ig = fsig(acc[2 * u][0]);
            float fg = fsig(acc[2 * u][1]);
            float gg = ftanh(acc[2 * u + 1][0]);
            float og = fsig(acc[2 * u + 1][1]);
            c0[u] = fmaf(fg, c0[u], ig * gg);
            Hs[0][cur ^ 1][u0 + u][lane] = og * ftanh(c0[u]);
        }
        __syncthreads();

        #pragma unroll
        for (int j = 0; j < 8; ++j) acc[j] = be1[j];
        #pragma unroll 4
        for (int k = 0; k < 64; ++k) {
            f2 hk = Hs[0][cur ^ 1][k][lane];
            #pragma unroll
            for (int j = 0; j < 8; ++j)
                acc[j] = __builtin_elementwise_fma(we1[k * 128 + j], hk, acc[j]);
        }
        #pragma unroll 4
        for (int k = 0; k < 64; ++k) {
            f2 hk = Hs[1][cur][k][lane];
            #pragma unroll
            for (int j = 0; j < 8; ++j)
                acc[j] = __builtin_elementwise_fma(we1[(64 + k) * 128 + j], hk, acc[j]);
        }
        #pragma unroll
        for (int u = 0; u < 4; ++u) {
            float ig = fsig(acc[2 * u][0]);
            float fg = fsig(acc[2 * u][1]);
            float gg = ftanh(acc[2 * u + 1][0]);
            float og = fsig(acc[2 * u + 1][1]);
            c1[u] = fmaf(fg, c1[u], ig * gg);
            Hs[1][cur ^ 1][u0 + u][lane] = og * ftanh(c1[u]);
        }
        __syncthreads();
        cur ^= 1;
        #pragma unroll
        for (int i = 0; i < IN_; ++i) x[i] = xn[i];
    }

    // ---------------- decoder ----------------
    float xp = src[(size_t)row * (S_ * IN_) + (S_ - 1) * IN_ + 3];
    const float fcb = ws[OFF_FCB];

    #pragma unroll 1
    for (int t = 0; t < T_; ++t) {
        f2 acc[8];
        f2 xs = xp;
        #pragma unroll
        for (int j = 0; j < 8; ++j)
            acc[j] = __builtin_elementwise_fma(wd0[j], xs, bd0[j]);
        #pragma unroll 4
        for (int k = 0; k < 64; ++k) {
            f2 hk = Hs[0][cur][k][lane];
            #pragma unroll
            for (int j = 0; j < 8; ++j)
                acc[j] = __builtin_elementwise_fma(wd0[(1 + k) * 128 + j], hk, acc[j]);
        }
        #pragma unroll
        for (int u = 0; u < 4; ++u) {
            float ig = fsig(acc[2 * u][0]);
            float fg = fsig(acc[2 * u][1]);
            float gg = ftanh(acc[2 * u + 1][0]);
            float og = fsig(acc[2 * u + 1][1]);
            c0[u] = fmaf(fg, c0[u], ig * gg);
            Hs[0][cur ^ 1][u0 + u][lane] = og * ftanh(c0[u]);
        }
        __syncthreads();

        #pragma unroll
        for (int j = 0; j < 8; ++j) acc[j] = bd1[j];
        #pragma unroll 4
        for (int k = 0; k < 64; ++k) {
            f2 hk = Hs[0][cur ^ 1][k][lane];
            #pragma unroll
            for (int j = 0; j < 8; ++j)
                acc[j] = __builtin_elementwise_fma(wd1[k * 128 + j], hk, acc[j]);
        }
        #pragma unroll 4
        for (int k = 0; k < 64; ++k) {
            f2 hk = Hs[1][cur][k][lane];
            #pragma unroll
            for (int j = 0; j < 8; ++j)
                acc[j] = __builtin_elementwise_fma(wd1[(64 + k) * 128 + j], hk, acc[j]);
        }
        #pragma unroll
        for (int u = 0; u < 4; ++u) {
            float ig = fsig(acc[2 * u][0]);
            float fg = fsig(acc[2 * u][1]);
            float gg = ftanh(acc[2 * u + 1][0]);
            float og = fsig(acc[2 * u + 1][1]);
            c1[u] = fmaf(fg, c1[u], ig * gg);
            Hs[1][cur ^ 1][u0 + u][lane] = og * ftanh(c1[u]);
        }
        __syncthreads();

        // fc head: pred = h1_new . fcW + fcb (all waves compute; wave 0 stores)
        float p = fcb;
        #pragma unroll 4
        for (int k = 0; k < 64; ++k)
            p = fmaf(fcw[k], Hs[1][cur ^ 1][k][lane], p);
        if (wave == 0) out[(size_t)row * T_ + t] = p;
        xp = p;
        cur ^= 1;
    }
}

extern "C" void kernel_launch(void* const* d_in, const int* in_sizes, int n_in,
                              void* d_out, int out_size, void* d_ws, size_t ws_size,
                              hipStream_t stream)
{
    const float* src = (const float*)d_in[0];
    float* ws  = (float*)d_ws;
    float* out = (float*)d_out;

    prep_kernel<<<(WS_TOT + 255) / 256, 256, 0, stream>>>(
        (const float*)d_in[1],  (const float*)d_in[2],
        (const float*)d_in[3],  (const float*)d_in[4],
        (const float*)d_in[5],  (const float*)d_in[6],
        (const float*)d_in[7],  (const float*)d_in[8],
        (const float*)d_in[9],  (const float*)d_in[10],
        (const float*)d_in[11], (const float*)d_in[12],
        (const float*)d_in[13], (const float*)d_in[14],
        (const float*)d_in[15], (const float*)d_in[16],
        (const float*)d_in[17], (const float*)d_in[18],
        ws);

    lstm_kernel<<<B_ / 64, 1024, 0, stream>>>(src, ws, out);
}